// Round 9
// baseline (1798.512 us; speedup 1.0000x reference)
//
#include <hip/hip_runtime.h>
#include <cstdint>
#include <cstddef>

#define B_ 128
#define T_ 500
#define I_ 512
#define H_ 1024
#define O_ 11
#define BETA 0.9f
#define THRESH 1.0f
#define K2_ 1536  // 3-term split: xh*wh + xl*wh + xh*wl

typedef __attribute__((ext_vector_type(4))) float f32x4;
typedef __attribute__((ext_vector_type(8))) short bf16x8;
typedef __attribute__((ext_vector_type(4))) unsigned int u32x4;

__device__ __forceinline__ unsigned short bf16_rne(float f) {
  unsigned int u = __float_as_uint(f);
  unsigned int r = u + 0x7FFFu + ((u >> 16) & 1u);
  return (unsigned short)(r >> 16);
}
__device__ __forceinline__ float bf16_to_f(unsigned short h) {
  return __uint_as_float(((unsigned int)h) << 16);
}

// ---------------- CSR build: row r = outgoing edges of neuron r, 128 slots -------------------
// entry = (w22 << 10) | target10; pad: w=0, tgt=(slot&63).
__global__ void k_csr(const float* __restrict__ W_rec, const float* __restrict__ mask,
                      unsigned int* __restrict__ csr, unsigned int* __restrict__ rowhi) {
  int r = blockIdx.x * 4 + (threadIdx.x >> 6);  // one wave per row
  int lane = threadIdx.x & 63;
  unsigned cnt = 0;
  const float* mrow = mask + (size_t)r * H_;
  const float* wrow = W_rec + (size_t)r * H_;
  for (int c = 0; c < 16; ++c) {
    float m = mrow[c * 64 + lane];
    bool nz = (m != 0.f);
    unsigned long long bb = __ballot(nz);
    unsigned pos = cnt + (unsigned)__popcll(bb & ((1ull << lane) - 1ull));
    if (nz) {
      float w = wrow[c * 64 + lane] * m;
      int wi = __float2int_rn(w * 8388608.f);  // 2^23
      wi = wi > 2097151 ? 2097151 : (wi < -2097151 ? -2097151 : wi);
      if (pos < 128u) csr[((size_t)r << 7) + pos] = (((unsigned)wi) << 10) | (unsigned)(c * 64 + lane);
    }
    cnt += (unsigned)__popcll(bb);
  }
  for (unsigned p = (cnt > 128u ? 128u : cnt) + (unsigned)lane; p < 128u; p += 64u)
    csr[((size_t)r << 7) + p] = (p & 63u);  // w=0 pad, lane-matched target (conflict-free)
  if (lane == 0) rowhi[r] = (cnt > 64u) ? 1u : 0u;
}

// ---------------- Wt [1024][1536] bf16: k2 = 3*i + c; c: 0->wh, 1->wh, 2->wl ------------------
__global__ void k_build_wt(const float* __restrict__ W_in, unsigned short* __restrict__ Wt) {
  int n = blockIdx.y;
  int k2 = blockIdx.x * 256 + threadIdx.x;  // 0..1535
  int i = k2 / 3;
  int c = k2 - 3 * i;
  float w = W_in[i * H_ + n];
  unsigned short hi = bf16_rne(w);
  unsigned short v = (c == 2) ? bf16_rne(w - bf16_to_f(hi)) : hi;
  Wt[(size_t)n * K2_ + k2] = v;
}

// ---------------- xs chunk [128*Tc][1536] bf16: per f32 j -> {xh, xl, xh} ---------------------
__global__ void k_build_xs(const float* __restrict__ x, unsigned short* __restrict__ xs,
                           int t0, int Tc) {
  int id = blockIdx.x * 256 + threadIdx.x;  // one thread = 8 consecutive f32 -> 24 bf16 (48B)
  int rr = id >> 6;                          // 64 octs per row (512/8)
  int oct = id & 63;
  int b = rr / Tc, tt = rr % Tc;
  const float4 v0 = *(const float4*)&x[((size_t)(b * T_ + t0 + tt)) * I_ + oct * 8];
  const float4 v1 = *(const float4*)&x[((size_t)(b * T_ + t0 + tt)) * I_ + oct * 8 + 4];
  alignas(16) unsigned short o[24];
  float vv[8] = {v0.x, v0.y, v0.z, v0.w, v1.x, v1.y, v1.z, v1.w};
#pragma unroll
  for (int j = 0; j < 8; ++j) {
    unsigned short hi = bf16_rne(vv[j]);
    unsigned short lo = bf16_rne(vv[j] - bf16_to_f(hi));
    o[3 * j + 0] = hi; o[3 * j + 1] = lo; o[3 * j + 2] = hi;
  }
  unsigned short* dst = xs + (size_t)rr * K2_ + oct * 24;
  *(u32x4*)(dst + 0) = *(u32x4*)(o + 0);
  *(u32x4*)(dst + 8) = *(u32x4*)(o + 8);
  *(u32x4*)(dst + 16) = *(u32x4*)(o + 16);
}

// ---------------- split-bf16 GEMM: drive[rr][h], K2=1536 --------------------------------------
#define LDA 72
__global__ __launch_bounds__(512, 1) void k_gemm(const unsigned short* __restrict__ xs,
                                                 const unsigned short* __restrict__ Wt,
                                                 float* __restrict__ drive) {
  __shared__ __align__(16) unsigned short As[128 * LDA];
  __shared__ __align__(16) unsigned short Bs[256 * LDA];
  int mt = blockIdx.x, nt = blockIdx.y;
  int tid = threadIdx.x;
  int lane = tid & 63, w = tid >> 6;
  int wr = w >> 2, wc = w & 3;
  f32x4 acc[4][4] = {};
  int arow = tid >> 2, aq = tid & 3;
  int brow = tid >> 1, bh = tid & 1;
  const unsigned short* xsrow = xs + (size_t)(mt * 128 + arow) * K2_ + aq * 16;
  const unsigned short* wtrow = Wt + (size_t)(nt * 256 + brow) * K2_ + bh * 32;
  for (int kt = 0; kt < K2_ / 64; ++kt) {
    u32x4 a0 = *(const u32x4*)(xsrow + kt * 64);
    u32x4 a1 = *(const u32x4*)(xsrow + kt * 64 + 8);
    u32x4 b0 = *(const u32x4*)(wtrow + kt * 64);
    u32x4 b1 = *(const u32x4*)(wtrow + kt * 64 + 8);
    u32x4 b2 = *(const u32x4*)(wtrow + kt * 64 + 16);
    u32x4 b3 = *(const u32x4*)(wtrow + kt * 64 + 24);
    __syncthreads();
    *(u32x4*)&As[arow * LDA + aq * 16] = a0;
    *(u32x4*)&As[arow * LDA + aq * 16 + 8] = a1;
    *(u32x4*)&Bs[brow * LDA + bh * 32] = b0;
    *(u32x4*)&Bs[brow * LDA + bh * 32 + 8] = b1;
    *(u32x4*)&Bs[brow * LDA + bh * 32 + 16] = b2;
    *(u32x4*)&Bs[brow * LDA + bh * 32 + 24] = b3;
    __syncthreads();
#pragma unroll
    for (int kk = 0; kk < 2; ++kk) {
      bf16x8 af[4], bf[4];
#pragma unroll
      for (int mi = 0; mi < 4; ++mi)
        af[mi] = *(const bf16x8*)&As[(wr * 64 + mi * 16 + (lane & 15)) * LDA + kk * 32 + (lane >> 4) * 8];
#pragma unroll
      for (int ni = 0; ni < 4; ++ni)
        bf[ni] = *(const bf16x8*)&Bs[(wc * 64 + ni * 16 + (lane & 15)) * LDA + kk * 32 + (lane >> 4) * 8];
#pragma unroll
      for (int mi = 0; mi < 4; ++mi)
#pragma unroll
        for (int ni = 0; ni < 4; ++ni)
          acc[mi][ni] = __builtin_amdgcn_mfma_f32_16x16x32_bf16(af[mi], bf[ni], acc[mi][ni], 0, 0, 0);
    }
  }
  int r0 = (lane >> 4) * 4, c0 = lane & 15;
#pragma unroll
  for (int mi = 0; mi < 4; ++mi) {
    int rowb = mt * 128 + wr * 64 + mi * 16 + r0;
#pragma unroll
    for (int ni = 0; ni < 4; ++ni) {
      int col = nt * 256 + wc * 64 + ni * 16 + c0;
#pragma unroll
      for (int r = 0; r < 4; ++r)
        drive[(size_t)(rowb + r) * H_ + col] = acc[mi][ni][r];
    }
  }
}

// -------- balanced scatter: ranks [F*wv/16, F*(wv+1)/16) over concatenated per-wave lists -----
__device__ __forceinline__ void scatter_balanced(
    const unsigned int* __restrict__ csr, const unsigned int* slotL,
    const unsigned int* cntL, int* accN, int lane, int wv) {
  unsigned cw = cntL[lane & 15];  // one ds_read, broadcast groups
  unsigned c0 = (unsigned)__builtin_amdgcn_readlane((int)cw, 0);
  unsigned c1 = (unsigned)__builtin_amdgcn_readlane((int)cw, 1);
  unsigned c2 = (unsigned)__builtin_amdgcn_readlane((int)cw, 2);
  unsigned c3 = (unsigned)__builtin_amdgcn_readlane((int)cw, 3);
  unsigned c4 = (unsigned)__builtin_amdgcn_readlane((int)cw, 4);
  unsigned c5 = (unsigned)__builtin_amdgcn_readlane((int)cw, 5);
  unsigned c6 = (unsigned)__builtin_amdgcn_readlane((int)cw, 6);
  unsigned c7 = (unsigned)__builtin_amdgcn_readlane((int)cw, 7);
  unsigned c8 = (unsigned)__builtin_amdgcn_readlane((int)cw, 8);
  unsigned c9 = (unsigned)__builtin_amdgcn_readlane((int)cw, 9);
  unsigned c10 = (unsigned)__builtin_amdgcn_readlane((int)cw, 10);
  unsigned c11 = (unsigned)__builtin_amdgcn_readlane((int)cw, 11);
  unsigned c12 = (unsigned)__builtin_amdgcn_readlane((int)cw, 12);
  unsigned c13 = (unsigned)__builtin_amdgcn_readlane((int)cw, 13);
  unsigned c14 = (unsigned)__builtin_amdgcn_readlane((int)cw, 14);
  unsigned c15 = (unsigned)__builtin_amdgcn_readlane((int)cw, 15);
  unsigned F = (((c0 + c1) + (c2 + c3)) + ((c4 + c5) + (c6 + c7))) +
               (((c8 + c9) + (c10 + c11)) + ((c12 + c13) + (c14 + c15)));
  unsigned lo = (F * (unsigned)wv) >> 4;
  unsigned hi = (F * ((unsigned)wv + 1u)) >> 4;
  unsigned g = 0, cum = 0, cg = c0;
  for (unsigned r = lo; r < hi; r += 8u) {
    // locate 8 consecutive ranks (monotone scalar walk)
#define SLOT(n) int sa##n = -1; { unsigned rn = r + n##u; if (rn < hi) { \
      while (cum + cg <= rn) { cum += cg; g = g + 1u; \
        cg = (unsigned)__builtin_amdgcn_readlane((int)cw, (int)(g & 15u)); } \
      sa##n = (int)((g << 6) + (rn - cum)); } }
    SLOT(0) SLOT(1) SLOT(2) SLOT(3) SLOT(4) SLOT(5) SLOT(6) SLOT(7)
#undef SLOT
    // slot reads (independent uniform-address ds_reads, one wait)
#define SREAD(n) unsigned ent##n = 0u; if (sa##n >= 0) ent##n = slotL[sa##n];
    SREAD(0) SREAD(1) SREAD(2) SREAD(3) SREAD(4) SREAD(5) SREAD(6) SREAD(7)
#undef SREAD
    // csr row loads: ALL issued before ANY atomic
#define SLOAD(n) unsigned ea##n = 0u, eb##n = 0u; bool hb##n = false; \
    if (sa##n >= 0) { \
      unsigned er = (unsigned)__builtin_amdgcn_readfirstlane((int)ent##n); \
      const unsigned int* rp = csr + ((size_t)(er & 1023u) << 7); \
      ea##n = rp[lane]; hb##n = (er & 4096u) != 0u; \
      if (hb##n) eb##n = rp[64 + lane]; }
    SLOAD(0) SLOAD(1) SLOAD(2) SLOAD(3) SLOAD(4) SLOAD(5) SLOAD(6) SLOAD(7)
#undef SLOAD
#define SATOM(n) if (sa##n >= 0) { \
      atomicAdd(&accN[ea##n & 1023u], ((int)ea##n) >> 10); \
      if (hb##n) atomicAdd(&accN[eb##n & 1023u], ((int)eb##n) >> 10); }
    SATOM(0) SATOM(1) SATOM(2) SATOM(3) SATOM(4) SATOM(5) SATOM(6) SATOM(7)
#undef SATOM
  }
}

// ---------------- recurrent scan: balanced listless scatter + 8-step drive prefetch -----------
__global__ __launch_bounds__(1024, 1) void k_rsnn(
    const float* __restrict__ drive, const unsigned int* __restrict__ csr,
    const unsigned int* __restrict__ rowhi,
    const float* __restrict__ h_bias, const float* __restrict__ W_out,
    const float* __restrict__ b_out,
    float* __restrict__ state_v, float* __restrict__ state_s, float* __restrict__ state_c,
    float* __restrict__ out, int t0, int Tc, int last) {
  __shared__ int accL[2][H_];
  __shared__ unsigned int slotL[H_];  // wave wv's compressed firing neurons at [wv*64 ..)
  __shared__ unsigned int cntL[16];
  __shared__ float red[H_];
  __shared__ float part[352];
  int tid = threadIdx.x;
  int b = blockIdx.x;
  int lane = tid & 63;
  int wv = tid >> 6;
  float bias = h_bias[tid];
  unsigned myslot = (unsigned)tid | (rowhi[tid] ? 4096u : 0u);
  float v, s, cnt;
  if (t0 == 0) { v = 0.f; s = 0.f; cnt = 0.f; }
  else { v = state_v[b * H_ + tid]; s = state_s[b * H_ + tid]; cnt = state_c[b * H_ + tid]; }
  accL[0][tid] = 0;
  accL[1][tid] = 0;
  __syncthreads();
  {  // scatter carried spikes into acc[0]
    unsigned long long bb = __ballot(s > 0.f);
    unsigned pos = (unsigned)__popcll(bb & ((1ull << lane) - 1ull));
    if (s > 0.f) slotL[(wv << 6) + pos] = myslot;
    if (lane == 0) cntL[wv] = (unsigned)__popcll(bb);
    __syncthreads();
    scatter_balanced(csr, slotL, cntL, accL[0], lane, wv);
    __syncthreads();
  }
  const float* dptr = drive + (size_t)b * Tc * H_ + tid;
  for (int t8 = 0; t8 < Tc; t8 += 8) {
    // 8 named-reg drive prefetches; vmcnt drain cost paid once per 8 steps
    float dd0 = (t8 + 0 < Tc) ? dptr[(size_t)(t8 + 0) * H_] : 0.f;
    float dd1 = (t8 + 1 < Tc) ? dptr[(size_t)(t8 + 1) * H_] : 0.f;
    float dd2 = (t8 + 2 < Tc) ? dptr[(size_t)(t8 + 2) * H_] : 0.f;
    float dd3 = (t8 + 3 < Tc) ? dptr[(size_t)(t8 + 3) * H_] : 0.f;
    float dd4 = (t8 + 4 < Tc) ? dptr[(size_t)(t8 + 4) * H_] : 0.f;
    float dd5 = (t8 + 5 < Tc) ? dptr[(size_t)(t8 + 5) * H_] : 0.f;
    float dd6 = (t8 + 6 < Tc) ? dptr[(size_t)(t8 + 6) * H_] : 0.f;
    float dd7 = (t8 + 7 < Tc) ? dptr[(size_t)(t8 + 7) * H_] : 0.f;
#define STEP(s_) if (t8 + s_ < Tc) { \
    int cur = (t8 + s_) & 1; \
    int ri = accL[cur][tid]; accL[cur][tid] = 0; \
    v = BETA * v + (dd##s_ + bias) + (float)ri * 1.1920929e-7f; \
    bool f = v > THRESH; \
    v -= f ? THRESH : 0.f; \
    cnt += f ? 1.f : 0.f; \
    s = f ? 1.f : 0.f; \
    unsigned long long bb = __ballot(f); \
    unsigned pos = (unsigned)__popcll(bb & ((1ull << lane) - 1ull)); \
    if (f) slotL[(wv << 6) + pos] = myslot; \
    if (lane == 0) cntL[wv] = (unsigned)__popcll(bb); \
    __syncthreads(); \
    scatter_balanced(csr, slotL, cntL, accL[cur ^ 1], lane, wv); \
    __syncthreads(); }
    STEP(0) STEP(1) STEP(2) STEP(3) STEP(4) STEP(5) STEP(6) STEP(7)
#undef STEP
  }
  if (!last) {
    state_v[b * H_ + tid] = v; state_s[b * H_ + tid] = s; state_c[b * H_ + tid] = cnt;
  } else {
    red[tid] = cnt;
    __syncthreads();
    if (tid < 352) {
      int o = tid >> 5, seg = tid & 31;
      float p = 0.f;
      for (int j = 0; j < 32; ++j) {
        int hh = seg * 32 + j;
        p += red[hh] * W_out[hh * O_ + o];
      }
      part[tid] = p;
    }
    __syncthreads();
    if (tid < O_) {
      float sum = 0.f;
      for (int g = 0; g < 32; ++g) sum += part[(tid << 5) + g];
      out[b * O_ + tid] = b_out[tid] + sum * (1.0f / (float)T_);
    }
  }
}

extern "C" void kernel_launch(void* const* d_in, const int* in_sizes, int n_in,
                              void* d_out, int out_size, void* d_ws, size_t ws_size,
                              hipStream_t stream) {
  (void)in_sizes; (void)n_in; (void)out_size;
  const float* x = (const float*)d_in[0];
  const float* W_in = (const float*)d_in[1];
  const float* W_rec = (const float*)d_in[2];
  const float* W_out = (const float*)d_in[3];
  const float* h_bias = (const float*)d_in[4];
  const float* b_out = (const float*)d_in[5];
  const float* mask = (const float*)d_in[6];
  float* out = (float*)d_out;

  char* ws = (char*)d_ws;
  size_t off = 0;
  auto alloc = [&](size_t bytes) {
    void* p = ws + off;
    off = (off + bytes + 255) & ~(size_t)255;
    return p;
  };
  unsigned short* Wt = (unsigned short*)alloc((size_t)H_ * K2_ * 2);
  unsigned int* csr = (unsigned int*)alloc((size_t)H_ * 128 * 4);
  unsigned int* rowhi = (unsigned int*)alloc((size_t)H_ * 4);
  float* st_v = (float*)alloc((size_t)B_ * H_ * 4);
  float* st_s = (float*)alloc((size_t)B_ * H_ * 4);
  float* st_c = (float*)alloc((size_t)B_ * H_ * 4);
  size_t fixed = off;

  size_t per_t = (size_t)128 * K2_ * 2 + (size_t)128 * 1024 * 4;
  int Tc = 1;
  if (ws_size > fixed + per_t) Tc = (int)((ws_size - fixed) / per_t);
  if (Tc > T_) Tc = T_;
  if (Tc < 1) Tc = 1;
  unsigned short* xs = (unsigned short*)alloc((size_t)128 * Tc * K2_ * 2);
  float* drive = (float*)alloc((size_t)128 * Tc * 1024 * 4);

  k_csr<<<dim3(256), dim3(256), 0, stream>>>(W_rec, mask, csr, rowhi);
  k_build_wt<<<dim3(6, 1024), dim3(256), 0, stream>>>(W_in, Wt);

  for (int t0 = 0; t0 < T_; t0 += Tc) {
    int tc = (Tc < T_ - t0) ? Tc : (T_ - t0);
    k_build_xs<<<dim3(32 * tc), dim3(256), 0, stream>>>(x, xs, t0, tc);
    k_gemm<<<dim3(tc, 4), dim3(512), 0, stream>>>(xs, Wt, drive);
    k_rsnn<<<dim3(128), dim3(1024), 0, stream>>>(drive, csr, rowhi, h_bias, W_out, b_out,
                                                 st_v, st_s, st_c, out, t0, tc,
                                                 (t0 + tc >= T_) ? 1 : 0);
  }
}

// Round 10
// 1047.552 us; speedup vs baseline: 1.7169x; 1.7169x over previous
//
#include <hip/hip_runtime.h>
#include <cstdint>
#include <cstddef>

#define B_ 128
#define T_ 500
#define I_ 512
#define H_ 1024
#define O_ 11
#define BETA 0.9f
#define THRESH 1.0f
#define K2_ 1536  // 3-term split: xh*wh + xl*wh + xh*wl

typedef __attribute__((ext_vector_type(4))) float f32x4;
typedef __attribute__((ext_vector_type(8))) short bf16x8;
typedef __attribute__((ext_vector_type(4))) unsigned int u32x4;

__device__ __forceinline__ unsigned short bf16_rne(float f) {
  unsigned int u = __float_as_uint(f);
  unsigned int r = u + 0x7FFFu + ((u >> 16) & 1u);
  return (unsigned short)(r >> 16);
}
__device__ __forceinline__ float bf16_to_f(unsigned short h) {
  return __uint_as_float(((unsigned int)h) << 16);
}

// ---------------- CSR build: row r = outgoing edges of neuron r, 128 slots -------------------
// entry = (w22 << 10) | target10; pad: w=0, tgt=(slot&63). Row 1024 = all-pad dummy row.
__global__ void k_csr(const float* __restrict__ W_rec, const float* __restrict__ mask,
                      unsigned int* __restrict__ csr, unsigned int* __restrict__ rowhi) {
  int r = blockIdx.x * 4 + (threadIdx.x >> 6);  // one wave per row
  if (r > 1024) return;
  int lane = threadIdx.x & 63;
  unsigned cnt = 0;
  if (r < 1024) {
    const float* mrow = mask + (size_t)r * H_;
    const float* wrow = W_rec + (size_t)r * H_;
    for (int c = 0; c < 16; ++c) {
      float m = mrow[c * 64 + lane];
      bool nz = (m != 0.f);
      unsigned long long bb = __ballot(nz);
      unsigned pos = cnt + (unsigned)__popcll(bb & ((1ull << lane) - 1ull));
      if (nz) {
        float w = wrow[c * 64 + lane] * m;
        int wi = __float2int_rn(w * 8388608.f);  // 2^23
        wi = wi > 2097151 ? 2097151 : (wi < -2097151 ? -2097151 : wi);
        if (pos < 128u) csr[((size_t)r << 7) + pos] = (((unsigned)wi) << 10) | (unsigned)(c * 64 + lane);
      }
      cnt += (unsigned)__popcll(bb);
    }
  }
  for (unsigned p = (cnt > 128u ? 128u : cnt) + (unsigned)lane; p < 128u; p += 64u)
    csr[((size_t)r << 7) + p] = (p & 63u);  // w=0 pad, lane-matched target (conflict-free)
  if (lane == 0) rowhi[r] = (cnt > 64u) ? 1u : 0u;
}

// ---------------- Wt [1024][1536] bf16: k2 = 3*i + c; c: 0->wh, 1->wh, 2->wl ------------------
__global__ void k_build_wt(const float* __restrict__ W_in, unsigned short* __restrict__ Wt) {
  int n = blockIdx.y;
  int k2 = blockIdx.x * 256 + threadIdx.x;  // 0..1535
  int i = k2 / 3;
  int c = k2 - 3 * i;
  float w = W_in[i * H_ + n];
  unsigned short hi = bf16_rne(w);
  unsigned short v = (c == 2) ? bf16_rne(w - bf16_to_f(hi)) : hi;
  Wt[(size_t)n * K2_ + k2] = v;
}

// ---------------- xs chunk [128*Tc][1536] bf16: per f32 j -> {xh, xl, xh} ---------------------
__global__ void k_build_xs(const float* __restrict__ x, unsigned short* __restrict__ xs,
                           int t0, int Tc) {
  int id = blockIdx.x * 256 + threadIdx.x;  // one thread = 8 consecutive f32 -> 24 bf16 (48B)
  int rr = id >> 6;                          // 64 octs per row (512/8)
  int oct = id & 63;
  int b = rr / Tc, tt = rr % Tc;
  const float4 v0 = *(const float4*)&x[((size_t)(b * T_ + t0 + tt)) * I_ + oct * 8];
  const float4 v1 = *(const float4*)&x[((size_t)(b * T_ + t0 + tt)) * I_ + oct * 8 + 4];
  alignas(16) unsigned short o[24];
  float vv[8] = {v0.x, v0.y, v0.z, v0.w, v1.x, v1.y, v1.z, v1.w};
#pragma unroll
  for (int j = 0; j < 8; ++j) {
    unsigned short hi = bf16_rne(vv[j]);
    unsigned short lo = bf16_rne(vv[j] - bf16_to_f(hi));
    o[3 * j + 0] = hi; o[3 * j + 1] = lo; o[3 * j + 2] = hi;
  }
  unsigned short* dst = xs + (size_t)rr * K2_ + oct * 24;
  *(u32x4*)(dst + 0) = *(u32x4*)(o + 0);
  *(u32x4*)(dst + 8) = *(u32x4*)(o + 8);
  *(u32x4*)(dst + 16) = *(u32x4*)(o + 16);
}

// ---------------- split-bf16 GEMM: drive[rr][h], K2=1536 --------------------------------------
#define LDA 72
__global__ __launch_bounds__(512, 1) void k_gemm(const unsigned short* __restrict__ xs,
                                                 const unsigned short* __restrict__ Wt,
                                                 float* __restrict__ drive) {
  __shared__ __align__(16) unsigned short As[128 * LDA];
  __shared__ __align__(16) unsigned short Bs[256 * LDA];
  int mt = blockIdx.x, nt = blockIdx.y;
  int tid = threadIdx.x;
  int lane = tid & 63, w = tid >> 6;
  int wr = w >> 2, wc = w & 3;
  f32x4 acc[4][4] = {};
  int arow = tid >> 2, aq = tid & 3;
  int brow = tid >> 1, bh = tid & 1;
  const unsigned short* xsrow = xs + (size_t)(mt * 128 + arow) * K2_ + aq * 16;
  const unsigned short* wtrow = Wt + (size_t)(nt * 256 + brow) * K2_ + bh * 32;
  for (int kt = 0; kt < K2_ / 64; ++kt) {
    u32x4 a0 = *(const u32x4*)(xsrow + kt * 64);
    u32x4 a1 = *(const u32x4*)(xsrow + kt * 64 + 8);
    u32x4 b0 = *(const u32x4*)(wtrow + kt * 64);
    u32x4 b1 = *(const u32x4*)(wtrow + kt * 64 + 8);
    u32x4 b2 = *(const u32x4*)(wtrow + kt * 64 + 16);
    u32x4 b3 = *(const u32x4*)(wtrow + kt * 64 + 24);
    __syncthreads();
    *(u32x4*)&As[arow * LDA + aq * 16] = a0;
    *(u32x4*)&As[arow * LDA + aq * 16 + 8] = a1;
    *(u32x4*)&Bs[brow * LDA + bh * 32] = b0;
    *(u32x4*)&Bs[brow * LDA + bh * 32 + 8] = b1;
    *(u32x4*)&Bs[brow * LDA + bh * 32 + 16] = b2;
    *(u32x4*)&Bs[brow * LDA + bh * 32 + 24] = b3;
    __syncthreads();
#pragma unroll
    for (int kk = 0; kk < 2; ++kk) {
      bf16x8 af[4], bf[4];
#pragma unroll
      for (int mi = 0; mi < 4; ++mi)
        af[mi] = *(const bf16x8*)&As[(wr * 64 + mi * 16 + (lane & 15)) * LDA + kk * 32 + (lane >> 4) * 8];
#pragma unroll
      for (int ni = 0; ni < 4; ++ni)
        bf[ni] = *(const bf16x8*)&Bs[(wc * 64 + ni * 16 + (lane & 15)) * LDA + kk * 32 + (lane >> 4) * 8];
#pragma unroll
      for (int mi = 0; mi < 4; ++mi)
#pragma unroll
        for (int ni = 0; ni < 4; ++ni)
          acc[mi][ni] = __builtin_amdgcn_mfma_f32_16x16x32_bf16(af[mi], bf[ni], acc[mi][ni], 0, 0, 0);
    }
  }
  int r0 = (lane >> 4) * 4, c0 = lane & 15;
#pragma unroll
  for (int mi = 0; mi < 4; ++mi) {
    int rowb = mt * 128 + wr * 64 + mi * 16 + r0;
#pragma unroll
    for (int ni = 0; ni < 4; ++ni) {
      int col = nt * 256 + wc * 64 + ni * 16 + c0;
#pragma unroll
      for (int r = 0; r < 4; ++r)
        drive[(size_t)(rowb + r) * H_ + col] = acc[mi][ni][r];
    }
  }
}

// ---------------- one RSNN step: R7 scatter (contiguous chunks, named-reg 8-slot batches) -----
__device__ __forceinline__ void step_one(
    float dcur, int cur, int tid, int lane, unsigned wvu, unsigned myhi, float bias,
    const unsigned int* __restrict__ csr, int* accL, unsigned int* listL, unsigned int* fcL,
    float& v, float& s, float& cnt) {
  unsigned F = (unsigned)__builtin_amdgcn_readfirstlane((int)fcL[cur]);
  unsigned lo = (F * wvu) >> 4;
  unsigned hi = (F * (wvu + 1u)) >> 4;
  for (unsigned i0 = lo; i0 < hi; i0 += 8u) {
    unsigned idx = i0 + ((unsigned)lane & 7u);
    unsigned packed = listL[idx < hi ? idx : (hi - 1u)];  // one ds_read per 8 slots
#define EDECL(n) unsigned e##n = (i0 + n##u < hi) ? (unsigned)__builtin_amdgcn_readlane((int)packed, n) : 1024u; \
                 unsigned ea##n = 0u, eb##n = 0u;
    EDECL(0) EDECL(1) EDECL(2) EDECL(3) EDECL(4) EDECL(5) EDECL(6) EDECL(7)
#undef EDECL
#define ELOAD(n) if (e##n != 1024u) { \
      const unsigned int* rp = csr + ((size_t)(e##n & 1023u) << 7); \
      ea##n = rp[lane]; \
      if (e##n & 4096u) eb##n = rp[64 + lane]; }
    ELOAD(0) ELOAD(1) ELOAD(2) ELOAD(3) ELOAD(4) ELOAD(5) ELOAD(6) ELOAD(7)
#undef ELOAD
#define EATOM(n) if (e##n != 1024u) { \
      atomicAdd(&accL[ea##n & 1023u], ((int)ea##n) >> 10); \
      if (e##n & 4096u) atomicAdd(&accL[eb##n & 1023u], ((int)eb##n) >> 10); }
    EATOM(0) EATOM(1) EATOM(2) EATOM(3) EATOM(4) EATOM(5) EATOM(6) EATOM(7)
#undef EATOM
  }
  __syncthreads();
  int ri = accL[tid];
  accL[tid] = 0;
  v = BETA * v + (dcur + bias) + (float)ri * 1.1920929e-7f;  // 2^-23
  bool f = v > THRESH;
  v -= f ? THRESH : 0.f;
  cnt += f ? 1.f : 0.f;
  s = f ? 1.f : 0.f;
  unsigned long long bb = __ballot(f);
  unsigned n = (unsigned)__popcll(bb);
  unsigned pos = (unsigned)__popcll(bb & ((1ull << lane) - 1ull));
  unsigned wb = 0;
  if (lane == 0) wb = atomicAdd(&fcL[cur ^ 1], n);
  wb = (unsigned)__builtin_amdgcn_readfirstlane((int)wb);
  if (f) listL[wb + pos] = (unsigned)tid | myhi;
  if (tid == 0) fcL[cur] = 0;
  __syncthreads();
}

// ---------------- recurrent scan: R7 + 8-deep named-reg drive prefetch ------------------------
__global__ __launch_bounds__(1024, 1) void k_rsnn(
    const float* __restrict__ drive, const unsigned int* __restrict__ csr,
    const unsigned int* __restrict__ rowhi,
    const float* __restrict__ h_bias, const float* __restrict__ W_out,
    const float* __restrict__ b_out,
    float* __restrict__ state_v, float* __restrict__ state_s, float* __restrict__ state_c,
    float* __restrict__ out, int t0, int Tc, int last) {
  __shared__ int accL[H_];
  __shared__ unsigned int listL[H_];
  __shared__ unsigned int fcL[2];
  __shared__ float red[H_];
  __shared__ float part[352];
  int tid = threadIdx.x;
  int b = blockIdx.x;
  int lane = tid & 63;
  unsigned wvu = (unsigned)__builtin_amdgcn_readfirstlane(tid >> 6);
  float bias = h_bias[tid];
  unsigned myhi = rowhi[tid] << 12;
  float v, s, cnt;
  if (t0 == 0) { v = 0.f; s = 0.f; cnt = 0.f; }
  else { v = state_v[b * H_ + tid]; s = state_s[b * H_ + tid]; cnt = state_c[b * H_ + tid]; }
  accL[tid] = 0;
  if (tid < 2) fcL[tid] = 0;
  __syncthreads();
  {  // initial firing list from carried state
    bool f0 = s > 0.f;
    unsigned long long bb = __ballot(f0);
    unsigned n = (unsigned)__popcll(bb);
    unsigned pos = (unsigned)__popcll(bb & ((1ull << lane) - 1ull));
    unsigned wb = 0;
    if (lane == 0) wb = atomicAdd(&fcL[0], n);
    wb = (unsigned)__builtin_amdgcn_readfirstlane((int)wb);
    if (f0) listL[wb + pos] = (unsigned)tid | myhi;
  }
  __syncthreads();
  const float* dptr = drive + (size_t)b * Tc * H_ + tid;
  for (int t8 = 0; t8 < Tc; t8 += 8) {
    // 8 named-reg drive prefetches; barrier vmcnt drain paid once per 8 steps
    float dd0 = (t8 + 0 < Tc) ? dptr[(size_t)(t8 + 0) * H_] : 0.f;
    float dd1 = (t8 + 1 < Tc) ? dptr[(size_t)(t8 + 1) * H_] : 0.f;
    float dd2 = (t8 + 2 < Tc) ? dptr[(size_t)(t8 + 2) * H_] : 0.f;
    float dd3 = (t8 + 3 < Tc) ? dptr[(size_t)(t8 + 3) * H_] : 0.f;
    float dd4 = (t8 + 4 < Tc) ? dptr[(size_t)(t8 + 4) * H_] : 0.f;
    float dd5 = (t8 + 5 < Tc) ? dptr[(size_t)(t8 + 5) * H_] : 0.f;
    float dd6 = (t8 + 6 < Tc) ? dptr[(size_t)(t8 + 6) * H_] : 0.f;
    float dd7 = (t8 + 7 < Tc) ? dptr[(size_t)(t8 + 7) * H_] : 0.f;
#define STEP(s_) if (t8 + s_ < Tc) \
    step_one(dd##s_, (s_ & 1), tid, lane, wvu, myhi, bias, csr, accL, listL, fcL, v, s, cnt);
    STEP(0) STEP(1) STEP(2) STEP(3) STEP(4) STEP(5) STEP(6) STEP(7)
#undef STEP
  }
  if (!last) {
    state_v[b * H_ + tid] = v; state_s[b * H_ + tid] = s; state_c[b * H_ + tid] = cnt;
  } else {
    red[tid] = cnt;
    __syncthreads();
    if (tid < 352) {
      int o = tid >> 5, seg = tid & 31;
      float p = 0.f;
      for (int j = 0; j < 32; ++j) {
        int hh = seg * 32 + j;
        p += red[hh] * W_out[hh * O_ + o];
      }
      part[tid] = p;
    }
    __syncthreads();
    if (tid < O_) {
      float sum = 0.f;
      for (int g = 0; g < 32; ++g) sum += part[(tid << 5) + g];
      out[b * O_ + tid] = b_out[tid] + sum * (1.0f / (float)T_);
    }
  }
}

extern "C" void kernel_launch(void* const* d_in, const int* in_sizes, int n_in,
                              void* d_out, int out_size, void* d_ws, size_t ws_size,
                              hipStream_t stream) {
  (void)in_sizes; (void)n_in; (void)out_size;
  const float* x = (const float*)d_in[0];
  const float* W_in = (const float*)d_in[1];
  const float* W_rec = (const float*)d_in[2];
  const float* W_out = (const float*)d_in[3];
  const float* h_bias = (const float*)d_in[4];
  const float* b_out = (const float*)d_in[5];
  const float* mask = (const float*)d_in[6];
  float* out = (float*)d_out;

  char* ws = (char*)d_ws;
  size_t off = 0;
  auto alloc = [&](size_t bytes) {
    void* p = ws + off;
    off = (off + bytes + 255) & ~(size_t)255;
    return p;
  };
  unsigned short* Wt = (unsigned short*)alloc((size_t)H_ * K2_ * 2);
  unsigned int* csr = (unsigned int*)alloc((size_t)(H_ + 1) * 128 * 4);  // +1 dummy row
  unsigned int* rowhi = (unsigned int*)alloc((size_t)(H_ + 1) * 4);
  float* st_v = (float*)alloc((size_t)B_ * H_ * 4);
  float* st_s = (float*)alloc((size_t)B_ * H_ * 4);
  float* st_c = (float*)alloc((size_t)B_ * H_ * 4);
  size_t fixed = off;

  size_t per_t = (size_t)128 * K2_ * 2 + (size_t)128 * 1024 * 4;
  int Tc = 1;
  if (ws_size > fixed + per_t) Tc = (int)((ws_size - fixed) / per_t);
  if (Tc > T_) Tc = T_;
  if (Tc < 1) Tc = 1;
  unsigned short* xs = (unsigned short*)alloc((size_t)128 * Tc * K2_ * 2);
  float* drive = (float*)alloc((size_t)128 * Tc * 1024 * 4);

  k_csr<<<dim3(257), dim3(256), 0, stream>>>(W_rec, mask, csr, rowhi);
  k_build_wt<<<dim3(6, 1024), dim3(256), 0, stream>>>(W_in, Wt);

  for (int t0 = 0; t0 < T_; t0 += Tc) {
    int tc = (Tc < T_ - t0) ? Tc : (T_ - t0);
    k_build_xs<<<dim3(32 * tc), dim3(256), 0, stream>>>(x, xs, t0, tc);
    k_gemm<<<dim3(tc, 4), dim3(512), 0, stream>>>(xs, Wt, drive);
    k_rsnn<<<dim3(128), dim3(1024), 0, stream>>>(drive, csr, rowhi, h_bias, W_out, b_out,
                                                 st_v, st_s, st_c, out, t0, tc,
                                                 (t0 + tc >= T_) ? 1 : 0);
  }
}

// Round 11
// 999.024 us; speedup vs baseline: 1.8003x; 1.0486x over previous
//
#include <hip/hip_runtime.h>
#include <cstdint>
#include <cstddef>

#define B_ 128
#define T_ 500
#define I_ 512
#define H_ 1024
#define O_ 11
#define BETA 0.9f
#define THRESH 1.0f
#define K2_ 1536  // 3 regions of 512: [xh*wh | xl*wh | xh*wl]

typedef __attribute__((ext_vector_type(4))) float f32x4;
typedef __attribute__((ext_vector_type(8))) short bf16x8;
typedef __attribute__((ext_vector_type(4))) unsigned int u32x4;

__device__ __forceinline__ unsigned short bf16_rne(float f) {
  unsigned int u = __float_as_uint(f);
  unsigned int r = u + 0x7FFFu + ((u >> 16) & 1u);
  return (unsigned short)(r >> 16);
}
__device__ __forceinline__ float bf16_to_f(unsigned short h) {
  return __uint_as_float(((unsigned int)h) << 16);
}

// ---------------- CSR build: row r = outgoing edges of neuron r, 128 slots -------------------
// entry = (w22 << 10) | target10; pad: w=0, tgt=(slot&63).
__global__ void k_csr(const float* __restrict__ W_rec, const float* __restrict__ mask,
                      unsigned int* __restrict__ csr, unsigned int* __restrict__ rowhi) {
  int r = blockIdx.x * 4 + (threadIdx.x >> 6);  // one wave per row
  int lane = threadIdx.x & 63;
  unsigned cnt = 0;
  const float* mrow = mask + (size_t)r * H_;
  const float* wrow = W_rec + (size_t)r * H_;
  for (int c = 0; c < 16; ++c) {
    float m = mrow[c * 64 + lane];
    bool nz = (m != 0.f);
    unsigned long long bb = __ballot(nz);
    unsigned pos = cnt + (unsigned)__popcll(bb & ((1ull << lane) - 1ull));
    if (nz) {
      float w = wrow[c * 64 + lane] * m;
      int wi = __float2int_rn(w * 8388608.f);  // 2^23
      wi = wi > 2097151 ? 2097151 : (wi < -2097151 ? -2097151 : wi);
      if (pos < 128u) csr[((size_t)r << 7) + pos] = (((unsigned)wi) << 10) | (unsigned)(c * 64 + lane);
    }
    cnt += (unsigned)__popcll(bb);
  }
  for (unsigned p = (cnt > 128u ? 128u : cnt) + (unsigned)lane; p < 128u; p += 64u)
    csr[((size_t)r << 7) + p] = (p & 63u);  // w=0 pad, lane-matched target (conflict-free)
  if (lane == 0) rowhi[r] = (cnt > 64u) ? 1u : 0u;
}

// ---------------- Wt [1024][1536] bf16: i = k2 & 511, region c = k2 >> 9 ----------------------
// c=0: wh, c=1: wh, c=2: wl   (pairs with A regions xh, xl, xh)
__global__ void k_build_wt(const float* __restrict__ W_in, unsigned short* __restrict__ Wt) {
  int n = blockIdx.y;
  int k2 = blockIdx.x * 256 + threadIdx.x;  // 0..1535
  int i = k2 & 511;
  int c = k2 >> 9;
  float w = W_in[i * H_ + n];
  unsigned short hi = bf16_rne(w);
  unsigned short v = (c == 2) ? bf16_rne(w - bf16_to_f(hi)) : hi;
  Wt[(size_t)n * K2_ + k2] = v;
}

// ---------------- split-bf16 GEMM from RAW x: drive[rr][h], K2=1536 ---------------------------
// Grid 1-D with XCD panel affinity: blocks sharing an A-panel (same mt) have ids equal mod 8
// -> same XCD -> panel read from HBM once, re-read from that XCD's L2.
#define LDA 72
__global__ __launch_bounds__(512, 1) void k_gemm(const float* __restrict__ x,
                                                 const unsigned short* __restrict__ Wt,
                                                 float* __restrict__ drive,
                                                 int t0, int Tc) {
  __shared__ __align__(16) unsigned short As[128 * LDA];
  __shared__ __align__(16) unsigned short Bs[256 * LDA];
  int id = blockIdx.x;
  int mt = (id >> 5) * 8 + (id & 7);
  int nt = (id >> 3) & 3;
  if (mt >= Tc) return;
  int tid = threadIdx.x;
  int lane = tid & 63, w = tid >> 6;
  int wr = w >> 2, wc = w & 3;
  f32x4 acc[4][4] = {};
  int arow = tid >> 2, aq = tid & 3;   // A stage: 128 rows x 4 quarters (16 k-elems each)
  int brow = tid >> 1, bh = tid & 1;   // B stage: 256 rows x 2 halves (32 elems each)
  int rr = mt * 128 + arow;
  int bb = rr / Tc, tt = rr - bb * Tc;
  const float* xrow = x + ((size_t)(bb * T_ + t0 + tt)) * I_ + aq * 16;
  const unsigned short* wtrow = Wt + (size_t)(nt * 256 + brow) * K2_ + bh * 32;
  for (int kt = 0; kt < K2_ / 64; ++kt) {
    int creg = kt >> 3;            // 0:xh 1:xl 2:xh (wave-uniform)
    int i0 = (kt & 7) * 64;
    const float* ap = xrow + i0;
    float4 a0 = *(const float4*)(ap);
    float4 a1 = *(const float4*)(ap + 4);
    float4 a2 = *(const float4*)(ap + 8);
    float4 a3 = *(const float4*)(ap + 12);
    u32x4 b0 = *(const u32x4*)(wtrow + kt * 64);
    u32x4 b1 = *(const u32x4*)(wtrow + kt * 64 + 8);
    u32x4 b2 = *(const u32x4*)(wtrow + kt * 64 + 16);
    u32x4 b3 = *(const u32x4*)(wtrow + kt * 64 + 24);
    // convert 16 f32 -> 16 bf16 (hi or lo per region) in registers
    alignas(16) unsigned short o[16];
    float vv[16] = {a0.x, a0.y, a0.z, a0.w, a1.x, a1.y, a1.z, a1.w,
                    a2.x, a2.y, a2.z, a2.w, a3.x, a3.y, a3.z, a3.w};
#pragma unroll
    for (int j = 0; j < 16; ++j) {
      unsigned short hi = bf16_rne(vv[j]);
      o[j] = (creg == 1) ? bf16_rne(vv[j] - bf16_to_f(hi)) : hi;
    }
    __syncthreads();  // previous iter's LDS reads done
    *(u32x4*)&As[arow * LDA + aq * 16] = *(u32x4*)o;
    *(u32x4*)&As[arow * LDA + aq * 16 + 8] = *(u32x4*)(o + 8);
    *(u32x4*)&Bs[brow * LDA + bh * 32] = b0;
    *(u32x4*)&Bs[brow * LDA + bh * 32 + 8] = b1;
    *(u32x4*)&Bs[brow * LDA + bh * 32 + 16] = b2;
    *(u32x4*)&Bs[brow * LDA + bh * 32 + 24] = b3;
    __syncthreads();
#pragma unroll
    for (int kk = 0; kk < 2; ++kk) {
      bf16x8 af[4], bf[4];
#pragma unroll
      for (int mi = 0; mi < 4; ++mi)
        af[mi] = *(const bf16x8*)&As[(wr * 64 + mi * 16 + (lane & 15)) * LDA + kk * 32 + (lane >> 4) * 8];
#pragma unroll
      for (int ni = 0; ni < 4; ++ni)
        bf[ni] = *(const bf16x8*)&Bs[(wc * 64 + ni * 16 + (lane & 15)) * LDA + kk * 32 + (lane >> 4) * 8];
#pragma unroll
      for (int mi = 0; mi < 4; ++mi)
#pragma unroll
        for (int ni = 0; ni < 4; ++ni)
          acc[mi][ni] = __builtin_amdgcn_mfma_f32_16x16x32_bf16(af[mi], bf[ni], acc[mi][ni], 0, 0, 0);
    }
  }
  int r0 = (lane >> 4) * 4, c0 = lane & 15;
#pragma unroll
  for (int mi = 0; mi < 4; ++mi) {
    int rowb = mt * 128 + wr * 64 + mi * 16 + r0;
#pragma unroll
    for (int ni = 0; ni < 4; ++ni) {
      int col = nt * 256 + wc * 64 + ni * 16 + c0;
#pragma unroll
      for (int r = 0; r < 4; ++r)
        drive[(size_t)(rowb + r) * H_ + col] = acc[mi][ni][r];
    }
  }
}

// ---------------- one RSNN step: R7 scatter (contiguous chunks, named-reg 8-slot batches) -----
__device__ __forceinline__ void step_one(
    float dcur, int cur, int tid, int lane, unsigned wvu, unsigned myhi, float bias,
    const unsigned int* __restrict__ csr, int* accL, unsigned int* listL, unsigned int* fcL,
    float& v, float& s, float& cnt) {
  unsigned F = (unsigned)__builtin_amdgcn_readfirstlane((int)fcL[cur]);
  unsigned lo = (F * wvu) >> 4;
  unsigned hi = (F * (wvu + 1u)) >> 4;
  for (unsigned i0 = lo; i0 < hi; i0 += 8u) {
    unsigned idx = i0 + ((unsigned)lane & 7u);
    unsigned packed = listL[idx < hi ? idx : (hi - 1u)];  // one ds_read per 8 slots
#define EDECL(n) unsigned e##n = (i0 + n##u < hi) ? (unsigned)__builtin_amdgcn_readlane((int)packed, n) : 1024u; \
                 unsigned ea##n = 0u, eb##n = 0u;
    EDECL(0) EDECL(1) EDECL(2) EDECL(3) EDECL(4) EDECL(5) EDECL(6) EDECL(7)
#undef EDECL
#define ELOAD(n) if (e##n != 1024u) { \
      const unsigned int* rp = csr + ((size_t)(e##n & 1023u) << 7); \
      ea##n = rp[lane]; \
      if (e##n & 4096u) eb##n = rp[64 + lane]; }
    ELOAD(0) ELOAD(1) ELOAD(2) ELOAD(3) ELOAD(4) ELOAD(5) ELOAD(6) ELOAD(7)
#undef ELOAD
#define EATOM(n) if (e##n != 1024u) { \
      atomicAdd(&accL[ea##n & 1023u], ((int)ea##n) >> 10); \
      if (e##n & 4096u) atomicAdd(&accL[eb##n & 1023u], ((int)eb##n) >> 10); }
    EATOM(0) EATOM(1) EATOM(2) EATOM(3) EATOM(4) EATOM(5) EATOM(6) EATOM(7)
#undef EATOM
  }
  __syncthreads();
  int ri = accL[tid];
  accL[tid] = 0;
  v = BETA * v + (dcur + bias) + (float)ri * 1.1920929e-7f;  // 2^-23
  bool f = v > THRESH;
  v -= f ? THRESH : 0.f;
  cnt += f ? 1.f : 0.f;
  s = f ? 1.f : 0.f;
  unsigned long long bb = __ballot(f);
  unsigned n = (unsigned)__popcll(bb);
  unsigned pos = (unsigned)__popcll(bb & ((1ull << lane) - 1ull));
  unsigned wb = 0;
  if (lane == 0) wb = atomicAdd(&fcL[cur ^ 1], n);
  wb = (unsigned)__builtin_amdgcn_readfirstlane((int)wb);
  if (f) listL[wb + pos] = (unsigned)tid | myhi;
  if (tid == 0) fcL[cur] = 0;
  __syncthreads();
}

// ---------------- recurrent scan: R10 structure (725 us known-good) ---------------------------
__global__ __launch_bounds__(1024, 1) void k_rsnn(
    const float* __restrict__ drive, const unsigned int* __restrict__ csr,
    const unsigned int* __restrict__ rowhi,
    const float* __restrict__ h_bias, const float* __restrict__ W_out,
    const float* __restrict__ b_out,
    float* __restrict__ state_v, float* __restrict__ state_s, float* __restrict__ state_c,
    float* __restrict__ out, int t0, int Tc, int last) {
  __shared__ int accL[H_];
  __shared__ unsigned int listL[H_];
  __shared__ unsigned int fcL[2];
  __shared__ float red[H_];
  __shared__ float part[352];
  int tid = threadIdx.x;
  int b = blockIdx.x;
  int lane = tid & 63;
  unsigned wvu = (unsigned)__builtin_amdgcn_readfirstlane(tid >> 6);
  float bias = h_bias[tid];
  unsigned myhi = rowhi[tid] << 12;
  float v, s, cnt;
  if (t0 == 0) { v = 0.f; s = 0.f; cnt = 0.f; }
  else { v = state_v[b * H_ + tid]; s = state_s[b * H_ + tid]; cnt = state_c[b * H_ + tid]; }
  accL[tid] = 0;
  if (tid < 2) fcL[tid] = 0;
  __syncthreads();
  {  // initial firing list from carried state
    bool f0 = s > 0.f;
    unsigned long long bb = __ballot(f0);
    unsigned n = (unsigned)__popcll(bb);
    unsigned pos = (unsigned)__popcll(bb & ((1ull << lane) - 1ull));
    unsigned wb = 0;
    if (lane == 0) wb = atomicAdd(&fcL[0], n);
    wb = (unsigned)__builtin_amdgcn_readfirstlane((int)wb);
    if (f0) listL[wb + pos] = (unsigned)tid | myhi;
  }
  __syncthreads();
  const float* dptr = drive + (size_t)b * Tc * H_ + tid;
  for (int t8 = 0; t8 < Tc; t8 += 8) {
    // 8 named-reg drive prefetches; barrier vmcnt drain paid once per 8 steps
    float dd0 = (t8 + 0 < Tc) ? dptr[(size_t)(t8 + 0) * H_] : 0.f;
    float dd1 = (t8 + 1 < Tc) ? dptr[(size_t)(t8 + 1) * H_] : 0.f;
    float dd2 = (t8 + 2 < Tc) ? dptr[(size_t)(t8 + 2) * H_] : 0.f;
    float dd3 = (t8 + 3 < Tc) ? dptr[(size_t)(t8 + 3) * H_] : 0.f;
    float dd4 = (t8 + 4 < Tc) ? dptr[(size_t)(t8 + 4) * H_] : 0.f;
    float dd5 = (t8 + 5 < Tc) ? dptr[(size_t)(t8 + 5) * H_] : 0.f;
    float dd6 = (t8 + 6 < Tc) ? dptr[(size_t)(t8 + 6) * H_] : 0.f;
    float dd7 = (t8 + 7 < Tc) ? dptr[(size_t)(t8 + 7) * H_] : 0.f;
#define STEP(s_) if (t8 + s_ < Tc) \
    step_one(dd##s_, (s_ & 1), tid, lane, wvu, myhi, bias, csr, accL, listL, fcL, v, s, cnt);
    STEP(0) STEP(1) STEP(2) STEP(3) STEP(4) STEP(5) STEP(6) STEP(7)
#undef STEP
  }
  if (!last) {
    state_v[b * H_ + tid] = v; state_s[b * H_ + tid] = s; state_c[b * H_ + tid] = cnt;
  } else {
    red[tid] = cnt;
    __syncthreads();
    if (tid < 352) {
      int o = tid >> 5, seg = tid & 31;
      float p = 0.f;
      for (int j = 0; j < 32; ++j) {
        int hh = seg * 32 + j;
        p += red[hh] * W_out[hh * O_ + o];
      }
      part[tid] = p;
    }
    __syncthreads();
    if (tid < O_) {
      float sum = 0.f;
      for (int g = 0; g < 32; ++g) sum += part[(tid << 5) + g];
      out[b * O_ + tid] = b_out[tid] + sum * (1.0f / (float)T_);
    }
  }
}

extern "C" void kernel_launch(void* const* d_in, const int* in_sizes, int n_in,
                              void* d_out, int out_size, void* d_ws, size_t ws_size,
                              hipStream_t stream) {
  (void)in_sizes; (void)n_in; (void)out_size;
  const float* x = (const float*)d_in[0];
  const float* W_in = (const float*)d_in[1];
  const float* W_rec = (const float*)d_in[2];
  const float* W_out = (const float*)d_in[3];
  const float* h_bias = (const float*)d_in[4];
  const float* b_out = (const float*)d_in[5];
  const float* mask = (const float*)d_in[6];
  float* out = (float*)d_out;

  char* ws = (char*)d_ws;
  size_t off = 0;
  auto alloc = [&](size_t bytes) {
    void* p = ws + off;
    off = (off + bytes + 255) & ~(size_t)255;
    return p;
  };
  unsigned short* Wt = (unsigned short*)alloc((size_t)H_ * K2_ * 2);
  unsigned int* csr = (unsigned int*)alloc((size_t)H_ * 128 * 4);
  unsigned int* rowhi = (unsigned int*)alloc((size_t)H_ * 4);
  float* st_v = (float*)alloc((size_t)B_ * H_ * 4);
  float* st_s = (float*)alloc((size_t)B_ * H_ * 4);
  float* st_c = (float*)alloc((size_t)B_ * H_ * 4);
  size_t fixed = off;

  size_t per_t = (size_t)128 * 1024 * 4;  // drive only (xs eliminated)
  int Tc = 1;
  if (ws_size > fixed + per_t) Tc = (int)((ws_size - fixed) / per_t);
  if (Tc > T_) Tc = T_;
  if (Tc < 1) Tc = 1;
  float* drive = (float*)alloc((size_t)128 * Tc * 1024 * 4);

  k_csr<<<dim3(256), dim3(256), 0, stream>>>(W_rec, mask, csr, rowhi);
  k_build_wt<<<dim3(6, 1024), dim3(256), 0, stream>>>(W_in, Wt);

  for (int t0 = 0; t0 < T_; t0 += Tc) {
    int tc = (Tc < T_ - t0) ? Tc : (T_ - t0);
    int groups = (tc + 7) / 8;
    k_gemm<<<dim3(groups * 32), dim3(512), 0, stream>>>(x, Wt, drive, t0, tc);
    k_rsnn<<<dim3(128), dim3(1024), 0, stream>>>(drive, csr, rowhi, h_bias, W_out, b_out,
                                                 st_v, st_s, st_c, out, t0, tc,
                                                 (t0 + tc >= T_) ? 1 : 0);
  }
}

// Round 12
// 862.520 us; speedup vs baseline: 2.0852x; 1.1583x over previous
//
#include <hip/hip_runtime.h>
#include <cstdint>
#include <cstddef>

#define B_ 128
#define T_ 500
#define I_ 512
#define H_ 1024
#define O_ 11
#define BETA 0.9f
#define THRESH 1.0f
#define K2_ 1536  // 3 regions of 512: [xh*wh | xl*wh | xh*wl]
#define LDA 72

typedef __attribute__((ext_vector_type(4))) float f32x4;
typedef __attribute__((ext_vector_type(8))) short bf16x8;
typedef __attribute__((ext_vector_type(4))) unsigned int u32x4;

struct ScanSmem {
  int accL[H_];
  unsigned int listL[H_];
  unsigned int fcL[2];
  float red[H_];
  float part[352];
};
struct GemmSmem {
  alignas(16) unsigned short As[128 * LDA];
  alignas(16) unsigned short Bs[256 * LDA];
};
union FusedSmem { ScanSmem s; GemmSmem g; };

__device__ __forceinline__ unsigned short bf16_rne(float f) {
  unsigned int u = __float_as_uint(f);
  unsigned int r = u + 0x7FFFu + ((u >> 16) & 1u);
  return (unsigned short)(r >> 16);
}
__device__ __forceinline__ float bf16_to_f(unsigned short h) {
  return __uint_as_float(((unsigned int)h) << 16);
}

// ---------------- CSR build: row r = outgoing edges of neuron r, 128 slots -------------------
__global__ void k_csr(const float* __restrict__ W_rec, const float* __restrict__ mask,
                      unsigned int* __restrict__ csr, unsigned int* __restrict__ rowhi) {
  int r = blockIdx.x * 4 + (threadIdx.x >> 6);
  int lane = threadIdx.x & 63;
  unsigned cnt = 0;
  const float* mrow = mask + (size_t)r * H_;
  const float* wrow = W_rec + (size_t)r * H_;
  for (int c = 0; c < 16; ++c) {
    float m = mrow[c * 64 + lane];
    bool nz = (m != 0.f);
    unsigned long long bb = __ballot(nz);
    unsigned pos = cnt + (unsigned)__popcll(bb & ((1ull << lane) - 1ull));
    if (nz) {
      float w = wrow[c * 64 + lane] * m;
      int wi = __float2int_rn(w * 8388608.f);  // 2^23
      wi = wi > 2097151 ? 2097151 : (wi < -2097151 ? -2097151 : wi);
      if (pos < 128u) csr[((size_t)r << 7) + pos] = (((unsigned)wi) << 10) | (unsigned)(c * 64 + lane);
    }
    cnt += (unsigned)__popcll(bb);
  }
  for (unsigned p = (cnt > 128u ? 128u : cnt) + (unsigned)lane; p < 128u; p += 64u)
    csr[((size_t)r << 7) + p] = (p & 63u);
  if (lane == 0) rowhi[r] = (cnt > 64u) ? 1u : 0u;
}

// ---------------- Wt [1024][1536] bf16: i = k2 & 511, region c = k2 >> 9 ----------------------
__global__ void k_build_wt(const float* __restrict__ W_in, unsigned short* __restrict__ Wt) {
  int n = blockIdx.y;
  int k2 = blockIdx.x * 256 + threadIdx.x;
  int i = k2 & 511;
  int c = k2 >> 9;
  float w = W_in[i * H_ + n];
  unsigned short hi = bf16_rne(w);
  unsigned short v = (c == 2) ? bf16_rne(w - bf16_to_f(hi)) : hi;
  Wt[(size_t)n * K2_ + k2] = v;
}

// ---------------- GEMM body: 1024 threads / 16 waves, 128x256 tile, 64x32 per wave ------------
__device__ __forceinline__ void gemm_body(const float* __restrict__ x,
                                          const unsigned short* __restrict__ Wt,
                                          float* __restrict__ drive, int t0, int Tc,
                                          int id, int tid,
                                          unsigned short* As, unsigned short* Bs) {
  int mt = (id >> 5) * 8 + (id & 7);  // XCD affinity: same mt -> ids equal mod 8
  int nt = (id >> 3) & 3;
  if (mt >= Tc) return;
  int lane = tid & 63, w = tid >> 6;
  int wr = w >> 3, wc = w & 7;  // 2 x 8 wave grid, each 64x32
  f32x4 acc[4][2] = {};
  int arow = tid >> 3, aoct = tid & 7;  // A stage: 128 rows x 8 thr x 8 f32
  int brow = tid >> 2, bq = tid & 3;    // B stage: 256 rows x 4 thr x 16 bf16
  int rr = mt * 128 + arow;
  int bb = rr / Tc, tt = rr - bb * Tc;
  const float* xrow = x + ((size_t)(bb * T_ + t0 + tt)) * I_ + aoct * 8;
  const unsigned short* wtrow = Wt + (size_t)(nt * 256 + brow) * K2_ + bq * 16;
  for (int kt = 0; kt < K2_ / 64; ++kt) {
    int creg = kt >> 3;         // 0:xh 1:xl 2:xh (wave-uniform)
    const float* ap = xrow + (kt & 7) * 64;
    float4 a0 = *(const float4*)(ap);
    float4 a1 = *(const float4*)(ap + 4);
    u32x4 b0 = *(const u32x4*)(wtrow + kt * 64);
    u32x4 b1 = *(const u32x4*)(wtrow + kt * 64 + 8);
    alignas(16) unsigned short o[8];
    float vv[8] = {a0.x, a0.y, a0.z, a0.w, a1.x, a1.y, a1.z, a1.w};
#pragma unroll
    for (int j = 0; j < 8; ++j) {
      unsigned short hi = bf16_rne(vv[j]);
      o[j] = (creg == 1) ? bf16_rne(vv[j] - bf16_to_f(hi)) : hi;
    }
    __syncthreads();  // previous iter's LDS reads done
    *(u32x4*)&As[arow * LDA + aoct * 8] = *(u32x4*)o;
    *(u32x4*)&Bs[brow * LDA + bq * 16] = b0;
    *(u32x4*)&Bs[brow * LDA + bq * 16 + 8] = b1;
    __syncthreads();
#pragma unroll
    for (int kk = 0; kk < 2; ++kk) {
      bf16x8 af[4], bf[2];
#pragma unroll
      for (int mi = 0; mi < 4; ++mi)
        af[mi] = *(const bf16x8*)&As[(wr * 64 + mi * 16 + (lane & 15)) * LDA + kk * 32 + (lane >> 4) * 8];
#pragma unroll
      for (int ni = 0; ni < 2; ++ni)
        bf[ni] = *(const bf16x8*)&Bs[(wc * 32 + ni * 16 + (lane & 15)) * LDA + kk * 32 + (lane >> 4) * 8];
#pragma unroll
      for (int mi = 0; mi < 4; ++mi)
#pragma unroll
        for (int ni = 0; ni < 2; ++ni)
          acc[mi][ni] = __builtin_amdgcn_mfma_f32_16x16x32_bf16(af[mi], bf[ni], acc[mi][ni], 0, 0, 0);
    }
  }
  int r0 = (lane >> 4) * 4, c0 = lane & 15;
#pragma unroll
  for (int mi = 0; mi < 4; ++mi) {
    int rowb = mt * 128 + wr * 64 + mi * 16 + r0;
#pragma unroll
    for (int ni = 0; ni < 2; ++ni) {
      int col = nt * 256 + wc * 32 + ni * 16 + c0;
#pragma unroll
      for (int r = 0; r < 4; ++r)
        drive[(size_t)(rowb + r) * H_ + col] = acc[mi][ni][r];
    }
  }
}

__global__ __launch_bounds__(1024, 1) void k_gemm(const float* __restrict__ x,
                                                  const unsigned short* __restrict__ Wt,
                                                  float* __restrict__ drive, int t0, int Tc) {
  __shared__ GemmSmem g;
  gemm_body(x, Wt, drive, t0, Tc, blockIdx.x, threadIdx.x, g.As, g.Bs);
}

// ---------------- one RSNN step (R11 structure, proven) ---------------------------------------
__device__ __forceinline__ void step_one(
    float dcur, int cur, int tid, int lane, unsigned wvu, unsigned myhi, float bias,
    const unsigned int* __restrict__ csr, int* accL, unsigned int* listL, unsigned int* fcL,
    float& v, float& s, float& cnt) {
  unsigned F = (unsigned)__builtin_amdgcn_readfirstlane((int)fcL[cur]);
  unsigned lo = (F * wvu) >> 4;
  unsigned hi = (F * (wvu + 1u)) >> 4;
  for (unsigned i0 = lo; i0 < hi; i0 += 8u) {
    unsigned idx = i0 + ((unsigned)lane & 7u);
    unsigned packed = listL[idx < hi ? idx : (hi - 1u)];  // one ds_read per 8 slots
#define EDECL(n) unsigned e##n = (i0 + n##u < hi) ? (unsigned)__builtin_amdgcn_readlane((int)packed, n) : 1024u; \
                 unsigned ea##n = 0u, eb##n = 0u;
    EDECL(0) EDECL(1) EDECL(2) EDECL(3) EDECL(4) EDECL(5) EDECL(6) EDECL(7)
#undef EDECL
#define ELOAD(n) if (e##n != 1024u) { \
      const unsigned int* rp = csr + ((size_t)(e##n & 1023u) << 7); \
      ea##n = rp[lane]; \
      if (e##n & 4096u) eb##n = rp[64 + lane]; }
    ELOAD(0) ELOAD(1) ELOAD(2) ELOAD(3) ELOAD(4) ELOAD(5) ELOAD(6) ELOAD(7)
#undef ELOAD
#define EATOM(n) if (e##n != 1024u) { \
      atomicAdd(&accL[ea##n & 1023u], ((int)ea##n) >> 10); \
      if (e##n & 4096u) atomicAdd(&accL[eb##n & 1023u], ((int)eb##n) >> 10); }
    EATOM(0) EATOM(1) EATOM(2) EATOM(3) EATOM(4) EATOM(5) EATOM(6) EATOM(7)
#undef EATOM
  }
  __syncthreads();
  int ri = accL[tid];
  accL[tid] = 0;
  v = BETA * v + (dcur + bias) + (float)ri * 1.1920929e-7f;  // 2^-23
  bool f = v > THRESH;
  v -= f ? THRESH : 0.f;
  cnt += f ? 1.f : 0.f;
  s = f ? 1.f : 0.f;
  unsigned long long bb = __ballot(f);
  unsigned n = (unsigned)__popcll(bb);
  unsigned pos = (unsigned)__popcll(bb & ((1ull << lane) - 1ull));
  unsigned wb = 0;
  if (lane == 0) wb = atomicAdd(&fcL[cur ^ 1], n);
  wb = (unsigned)__builtin_amdgcn_readfirstlane((int)wb);
  if (f) listL[wb + pos] = (unsigned)tid | myhi;
  if (tid == 0) fcL[cur] = 0;
  __syncthreads();
}

// ---------------- scan body (R11 structure, proven; parameterized smem) -----------------------
__device__ __forceinline__ void scan_body(
    const float* __restrict__ drive, const unsigned int* __restrict__ csr,
    const unsigned int* __restrict__ rowhi,
    const float* __restrict__ h_bias, const float* __restrict__ W_out,
    const float* __restrict__ b_out,
    float* __restrict__ state_v, float* __restrict__ state_s, float* __restrict__ state_c,
    float* __restrict__ out, int t0, int Tc, int last, int b, int tid, ScanSmem& sm) {
  int lane = tid & 63;
  unsigned wvu = (unsigned)__builtin_amdgcn_readfirstlane(tid >> 6);
  float bias = h_bias[tid];
  unsigned myhi = rowhi[tid] << 12;
  float v, s, cnt;
  if (t0 == 0) { v = 0.f; s = 0.f; cnt = 0.f; }
  else { v = state_v[b * H_ + tid]; s = state_s[b * H_ + tid]; cnt = state_c[b * H_ + tid]; }
  sm.accL[tid] = 0;
  if (tid < 2) sm.fcL[tid] = 0;
  __syncthreads();
  {  // initial firing list from carried state
    bool f0 = s > 0.f;
    unsigned long long bb = __ballot(f0);
    unsigned n = (unsigned)__popcll(bb);
    unsigned pos = (unsigned)__popcll(bb & ((1ull << lane) - 1ull));
    unsigned wb = 0;
    if (lane == 0) wb = atomicAdd(&sm.fcL[0], n);
    wb = (unsigned)__builtin_amdgcn_readfirstlane((int)wb);
    if (f0) sm.listL[wb + pos] = (unsigned)tid | myhi;
  }
  __syncthreads();
  const float* dptr = drive + (size_t)b * Tc * H_ + tid;
  for (int t8 = 0; t8 < Tc; t8 += 8) {
    float dd0 = (t8 + 0 < Tc) ? dptr[(size_t)(t8 + 0) * H_] : 0.f;
    float dd1 = (t8 + 1 < Tc) ? dptr[(size_t)(t8 + 1) * H_] : 0.f;
    float dd2 = (t8 + 2 < Tc) ? dptr[(size_t)(t8 + 2) * H_] : 0.f;
    float dd3 = (t8 + 3 < Tc) ? dptr[(size_t)(t8 + 3) * H_] : 0.f;
    float dd4 = (t8 + 4 < Tc) ? dptr[(size_t)(t8 + 4) * H_] : 0.f;
    float dd5 = (t8 + 5 < Tc) ? dptr[(size_t)(t8 + 5) * H_] : 0.f;
    float dd6 = (t8 + 6 < Tc) ? dptr[(size_t)(t8 + 6) * H_] : 0.f;
    float dd7 = (t8 + 7 < Tc) ? dptr[(size_t)(t8 + 7) * H_] : 0.f;
#define STEP(s_) if (t8 + s_ < Tc) \
    step_one(dd##s_, (s_ & 1), tid, lane, wvu, myhi, bias, csr, sm.accL, sm.listL, sm.fcL, v, s, cnt);
    STEP(0) STEP(1) STEP(2) STEP(3) STEP(4) STEP(5) STEP(6) STEP(7)
#undef STEP
  }
  if (!last) {
    state_v[b * H_ + tid] = v; state_s[b * H_ + tid] = s; state_c[b * H_ + tid] = cnt;
  } else {
    sm.red[tid] = cnt;
    __syncthreads();
    if (tid < 352) {
      int o = tid >> 5, seg = tid & 31;
      float p = 0.f;
      for (int j = 0; j < 32; ++j) {
        int hh = seg * 32 + j;
        p += sm.red[hh] * W_out[hh * O_ + o];
      }
      sm.part[tid] = p;
    }
    __syncthreads();
    if (tid < O_) {
      float sum = 0.f;
      for (int g = 0; g < 32; ++g) sum += sm.part[(tid << 5) + g];
      out[b * O_ + tid] = b_out[tid] + sum * (1.0f / (float)T_);
    }
  }
}

__global__ __launch_bounds__(1024, 1) void k_rsnn(
    const float* __restrict__ drive, const unsigned int* __restrict__ csr,
    const unsigned int* __restrict__ rowhi,
    const float* __restrict__ h_bias, const float* __restrict__ W_out,
    const float* __restrict__ b_out,
    float* __restrict__ state_v, float* __restrict__ state_s, float* __restrict__ state_c,
    float* __restrict__ out, int t0, int Tc, int last) {
  __shared__ ScanSmem sm;
  scan_body(drive, csr, rowhi, h_bias, W_out, b_out, state_v, state_s, state_c, out,
            t0, Tc, last, blockIdx.x, threadIdx.x, sm);
}

// ---------------- fused: blocks 0-127 scan chunk c; blocks 128+ GEMM chunk c+1 ----------------
__global__ __launch_bounds__(1024, 1) void k_fused(
    const float* __restrict__ drive_s, const unsigned int* __restrict__ csr,
    const unsigned int* __restrict__ rowhi,
    const float* __restrict__ h_bias, const float* __restrict__ W_out,
    const float* __restrict__ b_out,
    float* __restrict__ state_v, float* __restrict__ state_s, float* __restrict__ state_c,
    float* __restrict__ out, int t0s, int Tcs,
    const float* __restrict__ x, const unsigned short* __restrict__ Wt,
    float* __restrict__ drive_g, int t0g, int Tcg) {
  __shared__ FusedSmem sm;
  if (blockIdx.x < 128) {
    scan_body(drive_s, csr, rowhi, h_bias, W_out, b_out, state_v, state_s, state_c, out,
              t0s, Tcs, 0, blockIdx.x, threadIdx.x, sm.s);
  } else {
    gemm_body(x, Wt, drive_g, t0g, Tcg, blockIdx.x - 128, threadIdx.x, sm.g.As, sm.g.Bs);
  }
}

extern "C" void kernel_launch(void* const* d_in, const int* in_sizes, int n_in,
                              void* d_out, int out_size, void* d_ws, size_t ws_size,
                              hipStream_t stream) {
  (void)in_sizes; (void)n_in; (void)out_size;
  const float* x = (const float*)d_in[0];
  const float* W_in = (const float*)d_in[1];
  const float* W_rec = (const float*)d_in[2];
  const float* W_out = (const float*)d_in[3];
  const float* h_bias = (const float*)d_in[4];
  const float* b_out = (const float*)d_in[5];
  const float* mask = (const float*)d_in[6];
  float* out = (float*)d_out;

  char* ws = (char*)d_ws;
  size_t off = 0;
  auto alloc = [&](size_t bytes) {
    void* p = ws + off;
    off = (off + bytes + 255) & ~(size_t)255;
    return p;
  };
  unsigned short* Wt = (unsigned short*)alloc((size_t)H_ * K2_ * 2);
  unsigned int* csr = (unsigned int*)alloc((size_t)H_ * 128 * 4);
  unsigned int* rowhi = (unsigned int*)alloc((size_t)H_ * 4);
  float* st_v = (float*)alloc((size_t)B_ * H_ * 4);
  float* st_s = (float*)alloc((size_t)B_ * H_ * 4);
  float* st_c = (float*)alloc((size_t)B_ * H_ * 4);
  size_t fixed = off;

  size_t avail = ws_size > fixed ? ws_size - fixed : 0;
  const size_t per_t = (size_t)128 * 1024 * 4;  // 512 KB per timestep of drive
  int TC = 128;
  while (TC > 1 && 2u * (size_t)TC * per_t > avail) TC >>= 1;
  float* driveA = (float*)alloc((size_t)TC * per_t);
  float* driveB = (float*)alloc((size_t)TC * per_t);
  int C = (T_ + TC - 1) / TC;

  k_csr<<<dim3(256), dim3(256), 0, stream>>>(W_rec, mask, csr, rowhi);
  k_build_wt<<<dim3(6, 1024), dim3(256), 0, stream>>>(W_in, Wt);

  {  // GEMM for chunk 0 (full machine)
    int tc0 = T_ < TC ? T_ : TC;
    k_gemm<<<dim3(((tc0 + 7) / 8) * 32), dim3(1024), 0, stream>>>(x, Wt, driveA, 0, tc0);
  }
  for (int c = 0; c < C; ++c) {
    int t0 = c * TC;
    int tc = (T_ - t0) < TC ? (T_ - t0) : TC;
    float* bufS = (c & 1) ? driveB : driveA;
    if (c + 1 < C) {
      int t0n = (c + 1) * TC;
      int tcn = (T_ - t0n) < TC ? (T_ - t0n) : TC;
      float* bufG = ((c + 1) & 1) ? driveB : driveA;
      int gblocks = ((tcn + 7) / 8) * 32;
      k_fused<<<dim3(128 + gblocks), dim3(1024), 0, stream>>>(
          bufS, csr, rowhi, h_bias, W_out, b_out, st_v, st_s, st_c, out, t0, tc,
          x, Wt, bufG, t0n, tcn);
    } else {
      k_rsnn<<<dim3(128), dim3(1024), 0, stream>>>(bufS, csr, rowhi, h_bias, W_out, b_out,
                                                   st_v, st_s, st_c, out, t0, tc, 1);
    }
  }
}